// Round 21
// baseline (231.111 us; speedup 1.0000x reference)
//
#include <hip/hip_runtime.h>
#include <hip/hip_bf16.h>
#include <hip/hip_fp16.h>
#include <math.h>

#define G_ 32
#define H_ 12
#define D_ 768
#define HD_ 64
#define FF_ 3072
#define B_ 2
#define T_ 2048
#define SPAN_ 63
#define SPANC_ 129
#define EPSF 1e-5f

typedef short bf16x8 __attribute__((ext_vector_type(8)));
typedef short short4v __attribute__((ext_vector_type(4)));
typedef float f32x4 __attribute__((ext_vector_type(4)));
typedef unsigned char uchar16v __attribute__((ext_vector_type(16)));

__device__ __forceinline__ short f2bf(float f) {
    unsigned u = __builtin_bit_cast(unsigned, f);
    u = u + 0x7FFFu + ((u >> 16) & 1u);
    return (short)(u >> 16);
}

// OCP e5m2 = top byte of IEEE fp16 (same exponent bias, denormals align)
__device__ __forceinline__ unsigned char f2e5m2(float f) {
    unsigned short u = __half_as_ushort(__float2half(f));  // RNE to fp16
    u = (unsigned short)(u + 0x7F + ((u >> 8) & 1));       // RNE to top 8 bits
    return (unsigned char)(u >> 8);
}
__device__ __forceinline__ float e5m2f(unsigned u) {
    return __half2float(__ushort_as_half((unsigned short)(u << 8)));
}

// async global->LDS, 16B per lane; LDS dest = wave-uniform base + lane*16
__device__ __forceinline__ void gl_lds16(const void* g, void* l) {
    __builtin_amdgcn_global_load_lds(
        (const __attribute__((address_space(1))) unsigned int*)g,
        (__attribute__((address_space(3))) unsigned int*)l, 16, 0, 0);
}

// ---------------- LayerNorm (f32 in -> bf16 out): one wave per row ----------------
__global__ __launch_bounds__(256) void ln_bf16_kernel(const float* __restrict__ x,
                                                      const float* __restrict__ w,
                                                      const float* __restrict__ b,
                                                      short* __restrict__ out) {
    int wv = threadIdx.x >> 6;
    int lane = threadIdx.x & 63;
    int rowi = blockIdx.x * 4 + wv;
    const float* xr = x + (size_t)rowi * D_;
    float vals[12];
    float s = 0.f;
#pragma unroll
    for (int i = 0; i < 12; ++i) { vals[i] = xr[lane + i * 64]; s += vals[i]; }
#pragma unroll
    for (int off = 32; off > 0; off >>= 1) s += __shfl_xor(s, off, 64);
    float mean = s * (1.0f / D_);
    float vs = 0.f;
#pragma unroll
    for (int i = 0; i < 12; ++i) { float d = vals[i] - mean; vs += d * d; }
#pragma unroll
    for (int off = 32; off > 0; off >>= 1) vs += __shfl_xor(vs, off, 64);
    float rstd = rsqrtf(vs * (1.0f / D_) + EPSF);
    short* outr = out + (size_t)rowi * D_;
#pragma unroll
    for (int i = 0; i < 12; ++i) {
        int c = lane + i * 64;
        outr[c] = f2bf((vals[i] - mean) * rstd * w[c] + b[c]);
    }
}

// ---------------- fused transpose-cast for all 4 weights ----------------
__global__ __launch_bounds__(256) void tcast_all(const float* __restrict__ qkv_w,
                                                 const float* __restrict__ proj_w,
                                                 const float* __restrict__ ff1_w,
                                                 const float* __restrict__ ff2_w,
                                                 short* __restrict__ qkvt,
                                                 short* __restrict__ projt,
                                                 short* __restrict__ ff1t,
                                                 short* __restrict__ ff2t) {
    __shared__ float t[32][33];
    int bid = blockIdx.x;
    const float* W;
    short* Wt;
    int K, N, bx, lo;
    if (bid < 1728)      { W = qkv_w;  Wt = qkvt;  K = D_;  N = 3 * D_; bx = 72; lo = 0; }
    else if (bid < 2304) { W = proj_w; Wt = projt; K = D_;  N = D_;     bx = 24; lo = 1728; }
    else if (bid < 4608) { W = ff1_w;  Wt = ff1t;  K = D_;  N = FF_;    bx = 96; lo = 2304; }
    else                 { W = ff2_w;  Wt = ff2t;  K = FF_; N = D_;     bx = 24; lo = 4608; }
    int rblk = bid - lo;
    int n0 = (rblk % bx) * 32, k0 = (rblk / bx) * 32;
    int tid = threadIdx.x;
    int r = tid >> 3, c4 = (tid & 7) * 4;
    float4 v = *(const float4*)(W + (size_t)(k0 + r) * N + n0 + c4);
    t[r][c4 + 0] = v.x; t[r][c4 + 1] = v.y; t[r][c4 + 2] = v.z; t[r][c4 + 3] = v.w;
    __syncthreads();
    short4v o;
    o[0] = f2bf(t[c4 + 0][r]); o[1] = f2bf(t[c4 + 1][r]);
    o[2] = f2bf(t[c4 + 2][r]); o[3] = f2bf(t[c4 + 3][r]);
    *(short4v*)(Wt + (size_t)(n0 + r) * K + k0 + c4) = o;
}

// ---------------- quantize embedding tables to e5m2, 16B-padded rows ----------------
__global__ __launch_bounds__(256) void tables8_kernel(const float* __restrict__ rel_emb,
                                                      const float* __restrict__ demo_emb,
                                                      unsigned char* __restrict__ rel8,
                                                      unsigned char* __restrict__ demo8) {
    int i = blockIdx.x * 256 + threadIdx.x;
    if (i < SPAN_ * SPAN_ * 12) {
        int r = i / 12, h = i - r * 12;
        rel8[r * 16 + h] = f2e5m2(rel_emb[i]);
    }
    if (i < SPANC_ * SPAN_ * 12) {
        int r = i / 12, h = i - r * 12;
        demo8[r * 16 + h] = f2e5m2(demo_emb[i]);
    }
}

// ---------------- bias materialization: biasT[h][q][k] fp8-e5m2 ----------------
__global__ __launch_bounds__(256) void bias_build(
    const int* __restrict__ rowp, const int* __restrict__ colp,
    const int* __restrict__ drowp, const int* __restrict__ dcolp,
    const int* __restrict__ didp,
    const unsigned char* __restrict__ rel8, const unsigned char* __restrict__ demo8,
    unsigned char* __restrict__ biasT) {
    __shared__ unsigned char patch[12][16][80];
    int k0 = blockIdx.x * 64, q0 = blockIdx.y * 16;
    int tid = threadIdx.x;
    int qi = tid >> 4, kq = (tid & 15) * 4;
    int q = q0 + qi;
    int idq = didp[q];
    int rq = rowp[q], cq = colp[q], drq = drowp[q], dcq = dcolp[q];
#pragma unroll
    for (int j = 0; j < 4; ++j) {
        int k = k0 + kq + j;
        int idk = didp[k];
        uchar16v out = (uchar16v)(unsigned char)0;
        if (idq >= 0 && idk >= 0) {
            int dr = min(max(rq - rowp[k], -(G_ - 1)), G_ - 1) + (G_ - 1);
            int dc = min(max(cq - colp[k], -(G_ - 1)), G_ - 1) + (G_ - 1);
            uchar16v rv = *(const uchar16v*)(rel8 + (size_t)(dr * SPAN_ + dc) * 16);
            if (idq == idk) {
                int ddr = min(max(drq - drowp[k], -(G_ - 1)), G_ - 1) + (G_ - 1);
                int ddc = min(max(dcq - dcolp[k], -2 * G_), 2 * G_) + 2 * G_;
                uchar16v dv = *(const uchar16v*)(demo8 + (size_t)(ddr * SPANC_ + ddc) * 16);
#pragma unroll
                for (int h = 0; h < 12; ++h)
                    out[h] = f2e5m2(e5m2f(rv[h]) + e5m2f(dv[h]));
            } else {
                out = rv;
            }
        }
        int kl = kq + j;
#pragma unroll
        for (int h = 0; h < 12; ++h) patch[h][qi][kl] = out[h];
    }
    __syncthreads();
    for (int c = tid; c < 768; c += 256) {
        int rowid = c >> 2, off = (c & 3) * 16;
        int h = rowid >> 4, q2 = rowid & 15;
        *(uint4*)(biasT + (size_t)h * T_ * T_ + (size_t)(q0 + q2) * T_ + k0 + off) =
            *(const uint4*)&patch[h][q2][off];
    }
}

// ---------------- bf16 MFMA GEMM (4-wave, BM x 128): proj / ff2 ----------------
enum { EPI_NONE = 0, EPI_RES = 1, EPI_GELU = 2 };

template <int EPI, int BF16OUT, int BM>
__global__ __launch_bounds__(256, 4) void gemm_bf16(const short* __restrict__ A,
                                                    const short* __restrict__ Bt,
                                                    const float* __restrict__ bias,
                                                    const float* __restrict__ res,
                                                    void* __restrict__ Cv,
                                                    int M, int N, int K) {
    __shared__ short As[BM * 64];
    __shared__ short Bs[128 * 64];
    constexpr int WM = BM / 2;
    constexpr int MF = WM / 16;
    int tid = threadIdx.x;
    int l = tid & 63;
    int w = tid >> 6;
    int wm = w >> 1, wn = w & 1;
    int row0 = blockIdx.y * BM, col0 = blockIdx.x * 128;
    int g = l >> 4, c16 = l & 15;
    f32x4 zero = {0.f, 0.f, 0.f, 0.f};
    f32x4 acc[MF][4];
#pragma unroll
    for (int m = 0; m < MF; ++m)
#pragma unroll
        for (int n = 0; n < 4; ++n) acc[m][n] = zero;

    int srowA = w * (BM / 4) + (l >> 3);
    int srowB = w * 32 + (l >> 3);
    int sseg0 = (l & 7);

    for (int k0 = 0; k0 < K; k0 += 64) {
#pragma unroll
        for (int inst = 0; inst < BM / 32; ++inst) {
            int arow = srowA + inst * 8;
            int seg = sseg0 ^ (arow & 7);
            gl_lds16(A + (size_t)(row0 + arow) * K + k0 + seg * 8,
                     &As[(w * (BM / 4) + inst * 8) * 64]);
        }
#pragma unroll
        for (int inst = 0; inst < 4; ++inst) {
            int brow = srowB + inst * 8;
            int seg = sseg0 ^ (brow & 7);
            gl_lds16(Bt + (size_t)(col0 + brow) * K + k0 + seg * 8,
                     &Bs[(w * 32 + inst * 8) * 64]);
        }
        __syncthreads();
#pragma unroll
        for (int dk = 0; dk < 2; ++dk) {
            bf16x8 af[MF], bfr[4];
#pragma unroll
            for (int m = 0; m < MF; ++m) {
                int r = wm * WM + m * 16 + c16;
                af[m] = *(const bf16x8*)&As[r * 64 + (((dk * 4 + g) ^ (r & 7)) << 3)];
            }
#pragma unroll
            for (int n = 0; n < 4; ++n) {
                int r = wn * 64 + n * 16 + c16;
                bfr[n] = *(const bf16x8*)&Bs[r * 64 + (((dk * 4 + g) ^ (r & 7)) << 3)];
            }
#pragma unroll
            for (int m = 0; m < MF; ++m)
#pragma unroll
                for (int n = 0; n < 4; ++n)
                    acc[m][n] = __builtin_amdgcn_mfma_f32_16x16x32_bf16(af[m], bfr[n], acc[m][n], 0, 0, 0);
        }
        __syncthreads();
    }

#pragma unroll
    for (int m = 0; m < MF; ++m)
#pragma unroll
        for (int n = 0; n < 4; ++n) {
            int rrow = row0 + wm * WM + m * 16 + g * 4;
            int ccol = col0 + wn * 64 + n * 16 + c16;
            float bv = bias[ccol];
#pragma unroll
            for (int i = 0; i < 4; ++i) {
                float v = acc[m][n][i] + bv;
                if (EPI == EPI_GELU) v = 0.5f * v * (1.f + erff(v * 0.70710678118f));
                if (EPI == EPI_RES) v += res[(size_t)(rrow + i) * N + ccol];
                if (BF16OUT)
                    ((short*)Cv)[(size_t)(rrow + i) * N + ccol] = f2bf(v);
                else
                    ((float*)Cv)[(size_t)(rrow + i) * N + ccol] = v;
            }
        }
}

// ---------------- bf16 MFMA GEMM (2-wave, 128x128, wave-tile 64x128): qkv / ff1 ----------------
// Per dk: 12 ds_read_b128 feed 32 MFMA -> MFMA-bound (vs 8:16 LDS-bound in 4-wave).
template <int EPI>
__global__ __launch_bounds__(128, 2) void gemm_w2(const short* __restrict__ A,
                                                  const short* __restrict__ Bt,
                                                  const float* __restrict__ bias,
                                                  short* __restrict__ C,
                                                  int M, int N, int K) {
    __shared__ short As[128 * 64];
    __shared__ short Bs[128 * 64];
    int tid = threadIdx.x;
    int l = tid & 63;
    int w2 = tid >> 6;  // 0..1
    int row0 = blockIdx.y * 128, col0 = blockIdx.x * 128;
    int g = l >> 4, c16 = l & 15;
    f32x4 zero = {0.f, 0.f, 0.f, 0.f};
    f32x4 acc[4][8];
#pragma unroll
    for (int m = 0; m < 4; ++m)
#pragma unroll
        for (int n = 0; n < 8; ++n) acc[m][n] = zero;

    int srow = w2 * 8 + (l >> 3);  // row within each 16-row group
    int sseg0 = (l & 7);

    for (int k0 = 0; k0 < K; k0 += 64) {
#pragma unroll
        for (int inst = 0; inst < 8; ++inst) {
            int arow = inst * 16 + srow;
            int seg = sseg0 ^ (arow & 7);
            gl_lds16(A + (size_t)(row0 + arow) * K + k0 + seg * 8,
                     &As[(inst * 16 + w2 * 8) * 64]);
            gl_lds16(Bt + (size_t)(col0 + arow) * K + k0 + seg * 8,
                     &Bs[(inst * 16 + w2 * 8) * 64]);
        }
        __syncthreads();
#pragma unroll
        for (int dk = 0; dk < 2; ++dk) {
            bf16x8 af[4], bfr[8];
#pragma unroll
            for (int m = 0; m < 4; ++m) {
                int r = w2 * 64 + m * 16 + c16;
                af[m] = *(const bf16x8*)&As[r * 64 + (((dk * 4 + g) ^ (r & 7)) << 3)];
            }
#pragma unroll
            for (int n = 0; n < 8; ++n) {
                int r = n * 16 + c16;
                bfr[n] = *(const bf16x8*)&Bs[r * 64 + (((dk * 4 + g) ^ (r & 7)) << 3)];
            }
#pragma unroll
            for (int m = 0; m < 4; ++m)
#pragma unroll
                for (int n = 0; n < 8; ++n)
                    acc[m][n] = __builtin_amdgcn_mfma_f32_16x16x32_bf16(af[m], bfr[n], acc[m][n], 0, 0, 0);
        }
        __syncthreads();
    }

#pragma unroll
    for (int m = 0; m < 4; ++m)
#pragma unroll
        for (int n = 0; n < 8; ++n) {
            int rrow = row0 + w2 * 64 + m * 16 + g * 4;
            int ccol = col0 + n * 16 + c16;
            float bv = bias[ccol];
#pragma unroll
            for (int i = 0; i < 4; ++i) {
                float v = acc[m][n][i] + bv;
                if (EPI == EPI_GELU) v = 0.5f * v * (1.f + erff(v * 0.70710678118f));
                C[(size_t)(rrow + i) * N + ccol] = f2bf(v);
            }
        }
}

// ---------------- fused MFMA flash attention (round-14 structure + T5 setprio) ----------------
__global__ __launch_bounds__(256, 3) void attn_mfma(
    const short* __restrict__ qkv,
    const unsigned char* __restrict__ biasT,
    short* __restrict__ attn_o) {
    __shared__ short Ks[2][64 * 64];
    __shared__ short Vt[2][64 * 72];
    __shared__ short Pb[4][16 * 72];

    int tid = threadIdx.x, w = tid >> 6, l = tid & 63;
    int g = l >> 4, c16 = l & 15;
    int bid = blockIdx.x;
    int nb = (bid & 7) * 96 + (bid >> 3);   // XCD-chunk swizzle (768 = 8x96)
    int qt = nb & 31, bh = nb >> 5;
    int h = bh % H_, b = bh / H_;
    int q0 = qt * 64;
    const int QS = 3 * D_;
    const short* kvbase = qkv + (size_t)b * T_ * QS;

    bf16x8 qf[2];
    {
        int qrow = q0 + w * 16 + c16;
        const short* qp = kvbase + (size_t)qrow * QS + h * HD_;
        qf[0] = *(const bf16x8*)(qp + g * 8);
        qf[1] = *(const bf16x8*)(qp + 32 + g * 8);
    }
    const unsigned char* bptr[4];
#pragma unroll
    for (int i = 0; i < 4; ++i)
        bptr[i] = biasT + (size_t)h * T_ * T_ + (size_t)(q0 + w * 16 + g * 4 + i) * T_;

    int krow = tid >> 3, kseg = tid & 7;
    int kx = (kseg ^ (krow & 7)) << 3;
    const short* kgp = kvbase + D_ + h * HD_ + kseg * 8;
    int vk0 = (tid & 31) * 2, vd0 = (tid >> 5) * 8;
    int vbase = ((((vk0 >> 3) ^ (vd0 >> 3)) & 7) << 3) + (vk0 & 7);
    const short* vgp = kvbase + 2 * D_ + h * HD_ + vd0;

    f32x4 zero = {0.f, 0.f, 0.f, 0.f};
    f32x4 oacc[4];
#pragma unroll
    for (int nf = 0; nf < 4; ++nf) oacc[nf] = zero;
    float lsum[4] = {0.f, 0.f, 0.f, 0.f};

    bf16x8 kr0, kr1, vr0, vr1;
    kr0 = *(const bf16x8*)(kgp + (size_t)krow * QS);
    kr1 = *(const bf16x8*)(kgp + (size_t)(krow + 32) * QS);
    vr0 = *(const bf16x8*)(vgp + (size_t)vk0 * QS);
    vr1 = *(const bf16x8*)(vgp + (size_t)(vk0 + 1) * QS);
    *(bf16x8*)&Ks[0][krow * 64 + kx] = kr0;
    *(bf16x8*)&Ks[0][(krow + 32) * 64 + kx] = kr1;
#pragma unroll
    for (int j = 0; j < 8; ++j) {
        unsigned pr = (unsigned)(ushort)vr0[j] | ((unsigned)(ushort)vr1[j] << 16);
        *(unsigned*)&Vt[0][(vd0 + j) * 72 + vbase] = pr;
    }
    {
        const short* kg1 = kgp + (size_t)64 * QS;
        const short* vg1 = vgp + (size_t)64 * QS;
        kr0 = *(const bf16x8*)(kg1 + (size_t)krow * QS);
        kr1 = *(const bf16x8*)(kg1 + (size_t)(krow + 32) * QS);
        vr0 = *(const bf16x8*)(vg1 + (size_t)vk0 * QS);
        vr1 = *(const bf16x8*)(vg1 + (size_t)(vk0 + 1) * QS);
    }

    for (int t = 0; t < 32; ++t) {
        __syncthreads();
        const short* KsC = Ks[t & 1];
        const short* VtC = Vt[t & 1];
        short* KsN = Ks[(t + 1) & 1];
        short* VtN = Vt[(t + 1) & 1];
        *(bf16x8*)&KsN[krow * 64 + kx] = kr0;
        *(bf16x8*)&KsN[(krow + 32) * 64 + kx] = kr1;
#pragma unroll
        for (int j = 0; j < 8; ++j) {
            unsigned pr = (unsigned)(ushort)vr0[j] | ((unsigned)(ushort)vr1[j] << 16);
            *(unsigned*)&VtN[(vd0 + j) * 72 + vbase] = pr;
        }
        {
            int kb2 = ((t + 2) & 31) * 64;
            const short* kg2 = kgp + (size_t)kb2 * QS;
            const short* vg2 = vgp + (size_t)kb2 * QS;
            kr0 = *(const bf16x8*)(kg2 + (size_t)krow * QS);
            kr1 = *(const bf16x8*)(kg2 + (size_t)(krow + 32) * QS);
            vr0 = *(const bf16x8*)(vg2 + (size_t)vk0 * QS);
            vr1 = *(const bf16x8*)(vg2 + (size_t)(vk0 + 1) * QS);
        }
        int kb = t * 64;
        float bv[16];
#pragma unroll
        for (int nf = 0; nf < 4; ++nf)
#pragma unroll
            for (int i = 0; i < 4; ++i)
                bv[nf * 4 + i] = e5m2f(bptr[i][kb + nf * 16 + c16]);
        // ---- QK^T ----
        f32x4 sac[4];
#pragma unroll
        for (int nf = 0; nf < 4; ++nf) sac[nf] = zero;
        __builtin_amdgcn_s_setprio(1);
#pragma unroll
        for (int dk = 0; dk < 2; ++dk) {
#pragma unroll
            for (int nf = 0; nf < 4; ++nf) {
                int r = nf * 16 + c16;
                bf16x8 kf = *(const bf16x8*)&KsC[r * 64 + (((dk * 4 + g) ^ (r & 7)) << 3)];
                sac[nf] = __builtin_amdgcn_mfma_f32_16x16x32_bf16(qf[dk], kf, sac[nf], 0, 0, 0);
            }
        }
        __builtin_amdgcn_s_setprio(0);
        // ---- static-max softmax ----
#pragma unroll
        for (int nf = 0; nf < 4; ++nf)
#pragma unroll
            for (int i = 0; i < 4; ++i) {
                float e = __expf(fmaf(sac[nf][i], 0.125f, bv[nf * 4 + i]));
                sac[nf][i] = e;
                lsum[i] += e;
            }
        // ---- P -> wave-private LDS (chunk-swizzled by g) ----
        short* pbw = &Pb[w][0];
#pragma unroll
        for (int nf = 0; nf < 4; ++nf) {
            int chunkbase = nf * 2 + (c16 >> 3);
            int kpos = c16 & 7;
#pragma unroll
            for (int i = 0; i < 4; ++i)
                pbw[(g * 4 + i) * 72 + (((chunkbase ^ g) & 7) << 3) + kpos] = f2bf(sac[nf][i]);
        }
        // ---- PV ----
        __builtin_amdgcn_s_setprio(1);
#pragma unroll
        for (int dk = 0; dk < 2; ++dk) {
            bf16x8 pa = *(const bf16x8*)&pbw[c16 * 72 + (((dk * 4 + g) ^ (c16 >> 2)) & 7) * 8];
#pragma unroll
            for (int nf = 0; nf < 4; ++nf) {
                int d = nf * 16 + c16;
                bf16x8 vb = *(const bf16x8*)&VtC[d * 72 + (((dk * 4 + g) ^ (d >> 3)) & 7) * 8];
                oacc[nf] = __builtin_amdgcn_mfma_f32_16x16x32_bf16(pa, vb, oacc[nf], 0, 0, 0);
            }
        }
        __builtin_amdgcn_s_setprio(0);
    }

#pragma unroll
    for (int i = 0; i < 4; ++i) {
#pragma unroll
        for (int off = 1; off < 16; off <<= 1) lsum[i] += __shfl_xor(lsum[i], off, 64);
    }

#pragma unroll
    for (int nf = 0; nf < 4; ++nf)
#pragma unroll
        for (int i = 0; i < 4; ++i) {
            float o = oacc[nf][i] / lsum[i];
            int qq = q0 + w * 16 + g * 4 + i;
            attn_o[(size_t)(b * T_ + qq) * D_ + h * HD_ + nf * 16 + c16] = f2bf(o);
        }
}

// ---------------- launcher ----------------
extern "C" void kernel_launch(void* const* d_in, const int* in_sizes, int n_in,
                              void* d_out, int out_size, void* d_ws, size_t ws_size,
                              hipStream_t stream) {
    const float* x = (const float*)d_in[0];
    const int* rowp = (const int*)d_in[1];
    const int* colp = (const int*)d_in[2];
    const int* drowp = (const int*)d_in[3];
    const int* dcolp = (const int*)d_in[4];
    const int* didp = (const int*)d_in[5];
    // d_in[6] = is_sep (bool) — unused: is_sep <=> demo_id < 0 by construction
    const float* ln1_w = (const float*)d_in[7];
    const float* ln1_b = (const float*)d_in[8];
    const float* ln2_w = (const float*)d_in[9];
    const float* ln2_b = (const float*)d_in[10];
    const float* qkv_w = (const float*)d_in[11];
    const float* qkv_b = (const float*)d_in[12];
    const float* proj_w = (const float*)d_in[13];
    const float* proj_b = (const float*)d_in[14];
    const float* ff1_w = (const float*)d_in[15];
    const float* ff1_b = (const float*)d_in[16];
    const float* ff2_w = (const float*)d_in[17];
    const float* ff2_b = (const float*)d_in[18];
    const float* rel_emb = (const float*)d_in[19];
    const float* demo_emb = (const float*)d_in[20];
    float* out = (float*)d_out;

    const int M = B_ * T_;  // 4096
    char* p = (char*)d_ws;
    short* h1 = (short*)p;     p += (size_t)M * D_ * 2;
    short* qkvb = (short*)p;   p += (size_t)M * 3 * D_ * 2;
    short* attn_o = (short*)p; p += (size_t)M * D_ * 2;
    short* qkvt = (short*)p;   p += (size_t)(3 * D_) * D_ * 2;
    short* projt = (short*)p;  p += (size_t)D_ * D_ * 2;
    short* ff1t = (short*)p;   p += (size_t)FF_ * D_ * 2;
    short* ff2t = (short*)p;   p += (size_t)D_ * FF_ * 2;
    unsigned char* rel8 = (unsigned char*)p;  p += (size_t)SPAN_ * SPAN_ * 16;   // 63.5 KB
    unsigned char* demo8 = (unsigned char*)p; p += (size_t)SPANC_ * SPAN_ * 16;  // 130 KB
    // overlay: biasT (50.3 MB fp8, live until attention) aliases x2+h2+ffact.
    float* x2 = (float*)p;
    short* h2 = (short*)(p + (size_t)M * D_ * 4);
    short* ffact = (short*)(p + (size_t)M * D_ * 4 + (size_t)M * D_ * 2);
    unsigned char* biasT = (unsigned char*)p;

    // ---- precompute ----
    tables8_kernel<<<dim3((SPANC_ * SPAN_ * 12 + 255) / 256), 256, 0, stream>>>(
        rel_emb, demo_emb, rel8, demo8);
    bias_build<<<dim3(T_ / 64, T_ / 16), 256, 0, stream>>>(
        rowp, colp, drowp, dcolp, didp, rel8, demo8, biasT);
    tcast_all<<<dim3(6912), 256, 0, stream>>>(qkv_w, proj_w, ff1_w, ff2_w,
                                              qkvt, projt, ff1t, ff2t);

    // ---- main pipeline ----
    ln_bf16_kernel<<<dim3(M / 4), 256, 0, stream>>>(x, ln1_w, ln1_b, h1);

    gemm_w2<EPI_NONE><<<dim3(3 * D_ / 128, M / 128), 128, 0, stream>>>(
        h1, qkvt, qkv_b, qkvb, M, 3 * D_, D_);

    attn_mfma<<<dim3(B_ * H_ * (T_ / 64)), 256, 0, stream>>>(qkvb, biasT, attn_o);

    gemm_bf16<EPI_RES, 0, 64><<<dim3(D_ / 128, M / 64), 256, 0, stream>>>(
        attn_o, projt, proj_b, x, x2, M, D_, D_);

    ln_bf16_kernel<<<dim3(M / 4), 256, 0, stream>>>(x2, ln2_w, ln2_b, h2);

    gemm_w2<EPI_GELU><<<dim3(FF_ / 128, M / 128), 128, 0, stream>>>(
        h2, ff1t, ff1_b, ffact, M, FF_, D_);

    gemm_bf16<EPI_RES, 0, 64><<<dim3(D_ / 128, M / 64), 256, 0, stream>>>(
        ffact, ff2t, ff2_b, x2, out, M, D_, FF_);
}

// Round 22
// 229.168 us; speedup vs baseline: 1.0085x; 1.0085x over previous
//
#include <hip/hip_runtime.h>
#include <hip/hip_bf16.h>
#include <hip/hip_fp16.h>
#include <math.h>

#define G_ 32
#define H_ 12
#define D_ 768
#define HD_ 64
#define FF_ 3072
#define B_ 2
#define T_ 2048
#define SPAN_ 63
#define SPANC_ 129
#define EPSF 1e-5f

typedef short bf16x8 __attribute__((ext_vector_type(8)));
typedef short short4v __attribute__((ext_vector_type(4)));
typedef float f32x4 __attribute__((ext_vector_type(4)));
typedef unsigned char uchar16v __attribute__((ext_vector_type(16)));

__device__ __forceinline__ short f2bf(float f) {
    unsigned u = __builtin_bit_cast(unsigned, f);
    u = u + 0x7FFFu + ((u >> 16) & 1u);
    return (short)(u >> 16);
}

// OCP e5m2 = top byte of IEEE fp16 (same exponent bias, denormals align)
__device__ __forceinline__ unsigned char f2e5m2(float f) {
    unsigned short u = __half_as_ushort(__float2half(f));  // RNE to fp16
    u = (unsigned short)(u + 0x7F + ((u >> 8) & 1));       // RNE to top 8 bits
    return (unsigned char)(u >> 8);
}
__device__ __forceinline__ float e5m2f(unsigned u) {
    return __half2float(__ushort_as_half((unsigned short)(u << 8)));
}

// async global->LDS, 16B per lane; LDS dest = wave-uniform base + lane*16
__device__ __forceinline__ void gl_lds16(const void* g, void* l) {
    __builtin_amdgcn_global_load_lds(
        (const __attribute__((address_space(1))) unsigned int*)g,
        (__attribute__((address_space(3))) unsigned int*)l, 16, 0, 0);
}

// ---------------- LayerNorm (f32 in -> bf16 out): one wave per row ----------------
__global__ __launch_bounds__(256) void ln_bf16_kernel(const float* __restrict__ x,
                                                      const float* __restrict__ w,
                                                      const float* __restrict__ b,
                                                      short* __restrict__ out) {
    int wv = threadIdx.x >> 6;
    int lane = threadIdx.x & 63;
    int rowi = blockIdx.x * 4 + wv;
    const float* xr = x + (size_t)rowi * D_;
    float vals[12];
    float s = 0.f;
#pragma unroll
    for (int i = 0; i < 12; ++i) { vals[i] = xr[lane + i * 64]; s += vals[i]; }
#pragma unroll
    for (int off = 32; off > 0; off >>= 1) s += __shfl_xor(s, off, 64);
    float mean = s * (1.0f / D_);
    float vs = 0.f;
#pragma unroll
    for (int i = 0; i < 12; ++i) { float d = vals[i] - mean; vs += d * d; }
#pragma unroll
    for (int off = 32; off > 0; off >>= 1) vs += __shfl_xor(vs, off, 64);
    float rstd = rsqrtf(vs * (1.0f / D_) + EPSF);
    short* outr = out + (size_t)rowi * D_;
#pragma unroll
    for (int i = 0; i < 12; ++i) {
        int c = lane + i * 64;
        outr[c] = f2bf((vals[i] - mean) * rstd * w[c] + b[c]);
    }
}

// ---------------- fused transpose-cast for all 4 weights ----------------
__global__ __launch_bounds__(256) void tcast_all(const float* __restrict__ qkv_w,
                                                 const float* __restrict__ proj_w,
                                                 const float* __restrict__ ff1_w,
                                                 const float* __restrict__ ff2_w,
                                                 short* __restrict__ qkvt,
                                                 short* __restrict__ projt,
                                                 short* __restrict__ ff1t,
                                                 short* __restrict__ ff2t) {
    __shared__ float t[32][33];
    int bid = blockIdx.x;
    const float* W;
    short* Wt;
    int K, N, bx, lo;
    if (bid < 1728)      { W = qkv_w;  Wt = qkvt;  K = D_;  N = 3 * D_; bx = 72; lo = 0; }
    else if (bid < 2304) { W = proj_w; Wt = projt; K = D_;  N = D_;     bx = 24; lo = 1728; }
    else if (bid < 4608) { W = ff1_w;  Wt = ff1t;  K = D_;  N = FF_;    bx = 96; lo = 2304; }
    else                 { W = ff2_w;  Wt = ff2t;  K = FF_; N = D_;     bx = 24; lo = 4608; }
    int rblk = bid - lo;
    int n0 = (rblk % bx) * 32, k0 = (rblk / bx) * 32;
    int tid = threadIdx.x;
    int r = tid >> 3, c4 = (tid & 7) * 4;
    float4 v = *(const float4*)(W + (size_t)(k0 + r) * N + n0 + c4);
    t[r][c4 + 0] = v.x; t[r][c4 + 1] = v.y; t[r][c4 + 2] = v.z; t[r][c4 + 3] = v.w;
    __syncthreads();
    short4v o;
    o[0] = f2bf(t[c4 + 0][r]); o[1] = f2bf(t[c4 + 1][r]);
    o[2] = f2bf(t[c4 + 2][r]); o[3] = f2bf(t[c4 + 3][r]);
    *(short4v*)(Wt + (size_t)(n0 + r) * K + k0 + c4) = o;
}

// ---------------- quantize embedding tables to e5m2, 16B-padded rows ----------------
__global__ __launch_bounds__(256) void tables8_kernel(const float* __restrict__ rel_emb,
                                                      const float* __restrict__ demo_emb,
                                                      unsigned char* __restrict__ rel8,
                                                      unsigned char* __restrict__ demo8) {
    int i = blockIdx.x * 256 + threadIdx.x;
    if (i < SPAN_ * SPAN_ * 12) {
        int r = i / 12, h = i - r * 12;
        rel8[r * 16 + h] = f2e5m2(rel_emb[i]);
    }
    if (i < SPANC_ * SPAN_ * 12) {
        int r = i / 12, h = i - r * 12;
        demo8[r * 16 + h] = f2e5m2(demo_emb[i]);
    }
}

// ---------------- bias materialization: biasT[h][q][k] fp8-e5m2 ----------------
__global__ __launch_bounds__(256) void bias_build(
    const int* __restrict__ rowp, const int* __restrict__ colp,
    const int* __restrict__ drowp, const int* __restrict__ dcolp,
    const int* __restrict__ didp,
    const unsigned char* __restrict__ rel8, const unsigned char* __restrict__ demo8,
    unsigned char* __restrict__ biasT) {
    __shared__ unsigned char patch[12][16][80];
    int k0 = blockIdx.x * 64, q0 = blockIdx.y * 16;
    int tid = threadIdx.x;
    int qi = tid >> 4, kq = (tid & 15) * 4;
    int q = q0 + qi;
    int idq = didp[q];
    int rq = rowp[q], cq = colp[q], drq = drowp[q], dcq = dcolp[q];
#pragma unroll
    for (int j = 0; j < 4; ++j) {
        int k = k0 + kq + j;
        int idk = didp[k];
        uchar16v out = (uchar16v)(unsigned char)0;
        if (idq >= 0 && idk >= 0) {
            int dr = min(max(rq - rowp[k], -(G_ - 1)), G_ - 1) + (G_ - 1);
            int dc = min(max(cq - colp[k], -(G_ - 1)), G_ - 1) + (G_ - 1);
            uchar16v rv = *(const uchar16v*)(rel8 + (size_t)(dr * SPAN_ + dc) * 16);
            if (idq == idk) {
                int ddr = min(max(drq - drowp[k], -(G_ - 1)), G_ - 1) + (G_ - 1);
                int ddc = min(max(dcq - dcolp[k], -2 * G_), 2 * G_) + 2 * G_;
                uchar16v dv = *(const uchar16v*)(demo8 + (size_t)(ddr * SPANC_ + ddc) * 16);
#pragma unroll
                for (int h = 0; h < 12; ++h)
                    out[h] = f2e5m2(e5m2f(rv[h]) + e5m2f(dv[h]));
            } else {
                out = rv;
            }
        }
        int kl = kq + j;
#pragma unroll
        for (int h = 0; h < 12; ++h) patch[h][qi][kl] = out[h];
    }
    __syncthreads();
    for (int c = tid; c < 768; c += 256) {
        int rowid = c >> 2, off = (c & 3) * 16;
        int h = rowid >> 4, q2 = rowid & 15;
        *(uint4*)(biasT + (size_t)h * T_ * T_ + (size_t)(q0 + q2) * T_ + k0 + off) =
            *(const uint4*)&patch[h][q2][off];
    }
}

// ---------------- bf16 MFMA GEMM: C = A[M][K] * Bt[N][K]^T ----------------
enum { EPI_NONE = 0, EPI_RES = 1, EPI_GELU = 2 };

template <int EPI, int BF16OUT, int BM>
__global__ __launch_bounds__(256, 4) void gemm_bf16(const short* __restrict__ A,
                                                    const short* __restrict__ Bt,
                                                    const float* __restrict__ bias,
                                                    const float* __restrict__ res,
                                                    void* __restrict__ Cv,
                                                    int M, int N, int K) {
    __shared__ short As[BM * 64];
    __shared__ short Bs[128 * 64];
    constexpr int WM = BM / 2;
    constexpr int MF = WM / 16;
    int tid = threadIdx.x;
    int l = tid & 63;
    int w = tid >> 6;
    int wm = w >> 1, wn = w & 1;
    int row0 = blockIdx.y * BM, col0 = blockIdx.x * 128;
    int g = l >> 4, c16 = l & 15;
    f32x4 zero = {0.f, 0.f, 0.f, 0.f};
    f32x4 acc[MF][4];
#pragma unroll
    for (int m = 0; m < MF; ++m)
#pragma unroll
        for (int n = 0; n < 4; ++n) acc[m][n] = zero;

    int srowA = w * (BM / 4) + (l >> 3);
    int srowB = w * 32 + (l >> 3);
    int sseg0 = (l & 7);

    for (int k0 = 0; k0 < K; k0 += 64) {
#pragma unroll
        for (int inst = 0; inst < BM / 32; ++inst) {
            int arow = srowA + inst * 8;
            int seg = sseg0 ^ (arow & 7);
            gl_lds16(A + (size_t)(row0 + arow) * K + k0 + seg * 8,
                     &As[(w * (BM / 4) + inst * 8) * 64]);
        }
#pragma unroll
        for (int inst = 0; inst < 4; ++inst) {
            int brow = srowB + inst * 8;
            int seg = sseg0 ^ (brow & 7);
            gl_lds16(Bt + (size_t)(col0 + brow) * K + k0 + seg * 8,
                     &Bs[(w * 32 + inst * 8) * 64]);
        }
        __syncthreads();
#pragma unroll
        for (int dk = 0; dk < 2; ++dk) {
            bf16x8 af[MF], bfr[4];
#pragma unroll
            for (int m = 0; m < MF; ++m) {
                int r = wm * WM + m * 16 + c16;
                af[m] = *(const bf16x8*)&As[r * 64 + (((dk * 4 + g) ^ (r & 7)) << 3)];
            }
#pragma unroll
            for (int n = 0; n < 4; ++n) {
                int r = wn * 64 + n * 16 + c16;
                bfr[n] = *(const bf16x8*)&Bs[r * 64 + (((dk * 4 + g) ^ (r & 7)) << 3)];
            }
#pragma unroll
            for (int m = 0; m < MF; ++m)
#pragma unroll
                for (int n = 0; n < 4; ++n)
                    acc[m][n] = __builtin_amdgcn_mfma_f32_16x16x32_bf16(af[m], bfr[n], acc[m][n], 0, 0, 0);
        }
        __syncthreads();
    }

#pragma unroll
    for (int m = 0; m < MF; ++m)
#pragma unroll
        for (int n = 0; n < 4; ++n) {
            int rrow = row0 + wm * WM + m * 16 + g * 4;
            int ccol = col0 + wn * 64 + n * 16 + c16;
            float bv = bias[ccol];
#pragma unroll
            for (int i = 0; i < 4; ++i) {
                float v = acc[m][n][i] + bv;
                if (EPI == EPI_GELU) v = 0.5f * v * (1.f + erff(v * 0.70710678118f));
                if (EPI == EPI_RES) v += res[(size_t)(rrow + i) * N + ccol];
                if (BF16OUT)
                    ((short*)Cv)[(size_t)(rrow + i) * N + ccol] = f2bf(v);
                else
                    ((float*)Cv)[(size_t)(rrow + i) * N + ccol] = v;
            }
        }
}

// ---------------- fused MFMA flash attention (round-14 structure + T5 setprio) ----------------
__global__ __launch_bounds__(256, 3) void attn_mfma(
    const short* __restrict__ qkv,
    const unsigned char* __restrict__ biasT,
    short* __restrict__ attn_o) {
    __shared__ short Ks[2][64 * 64];
    __shared__ short Vt[2][64 * 72];
    __shared__ short Pb[4][16 * 72];

    int tid = threadIdx.x, w = tid >> 6, l = tid & 63;
    int g = l >> 4, c16 = l & 15;
    int bid = blockIdx.x;
    int nb = (bid & 7) * 96 + (bid >> 3);   // XCD-chunk swizzle (768 = 8x96)
    int qt = nb & 31, bh = nb >> 5;
    int h = bh % H_, b = bh / H_;
    int q0 = qt * 64;
    const int QS = 3 * D_;
    const short* kvbase = qkv + (size_t)b * T_ * QS;

    // Q fragments (A-operand)
    bf16x8 qf[2];
    {
        int qrow = q0 + w * 16 + c16;
        const short* qp = kvbase + (size_t)qrow * QS + h * HD_;
        qf[0] = *(const bf16x8*)(qp + g * 8);
        qf[1] = *(const bf16x8*)(qp + 32 + g * 8);
    }
    const unsigned char* bptr[4];
#pragma unroll
    for (int i = 0; i < 4; ++i)
        bptr[i] = biasT + (size_t)h * T_ * T_ + (size_t)(q0 + w * 16 + g * 4 + i) * T_;

    int krow = tid >> 3, kseg = tid & 7;
    int kx = (kseg ^ (krow & 7)) << 3;
    const short* kgp = kvbase + D_ + h * HD_ + kseg * 8;
    int vk0 = (tid & 31) * 2, vd0 = (tid >> 5) * 8;
    int vbase = ((((vk0 >> 3) ^ (vd0 >> 3)) & 7) << 3) + (vk0 & 7);
    const short* vgp = kvbase + 2 * D_ + h * HD_ + vd0;

    f32x4 zero = {0.f, 0.f, 0.f, 0.f};
    f32x4 oacc[4];
#pragma unroll
    for (int nf = 0; nf < 4; ++nf) oacc[nf] = zero;
    float lsum[4] = {0.f, 0.f, 0.f, 0.f};

    bf16x8 kr0, kr1, vr0, vr1;
    kr0 = *(const bf16x8*)(kgp + (size_t)krow * QS);
    kr1 = *(const bf16x8*)(kgp + (size_t)(krow + 32) * QS);
    vr0 = *(const bf16x8*)(vgp + (size_t)vk0 * QS);
    vr1 = *(const bf16x8*)(vgp + (size_t)(vk0 + 1) * QS);
    *(bf16x8*)&Ks[0][krow * 64 + kx] = kr0;
    *(bf16x8*)&Ks[0][(krow + 32) * 64 + kx] = kr1;
#pragma unroll
    for (int j = 0; j < 8; ++j) {
        unsigned pr = (unsigned)(ushort)vr0[j] | ((unsigned)(ushort)vr1[j] << 16);
        *(unsigned*)&Vt[0][(vd0 + j) * 72 + vbase] = pr;
    }
    {
        const short* kg1 = kgp + (size_t)64 * QS;
        const short* vg1 = vgp + (size_t)64 * QS;
        kr0 = *(const bf16x8*)(kg1 + (size_t)krow * QS);
        kr1 = *(const bf16x8*)(kg1 + (size_t)(krow + 32) * QS);
        vr0 = *(const bf16x8*)(vg1 + (size_t)vk0 * QS);
        vr1 = *(const bf16x8*)(vg1 + (size_t)(vk0 + 1) * QS);
    }

    for (int t = 0; t < 32; ++t) {
        __syncthreads();
        const short* KsC = Ks[t & 1];
        const short* VtC = Vt[t & 1];
        short* KsN = Ks[(t + 1) & 1];
        short* VtN = Vt[(t + 1) & 1];
        *(bf16x8*)&KsN[krow * 64 + kx] = kr0;
        *(bf16x8*)&KsN[(krow + 32) * 64 + kx] = kr1;
#pragma unroll
        for (int j = 0; j < 8; ++j) {
            unsigned pr = (unsigned)(ushort)vr0[j] | ((unsigned)(ushort)vr1[j] << 16);
            *(unsigned*)&VtN[(vd0 + j) * 72 + vbase] = pr;
        }
        {
            int kb2 = ((t + 2) & 31) * 64;
            const short* kg2 = kgp + (size_t)kb2 * QS;
            const short* vg2 = vgp + (size_t)kb2 * QS;
            kr0 = *(const bf16x8*)(kg2 + (size_t)krow * QS);
            kr1 = *(const bf16x8*)(kg2 + (size_t)(krow + 32) * QS);
            vr0 = *(const bf16x8*)(vg2 + (size_t)vk0 * QS);
            vr1 = *(const bf16x8*)(vg2 + (size_t)(vk0 + 1) * QS);
        }
        // ---- fp8 bias loads for this tile (coalesced bytes) ----
        int kb = t * 64;
        float bv[16];
#pragma unroll
        for (int nf = 0; nf < 4; ++nf)
#pragma unroll
            for (int i = 0; i < 4; ++i)
                bv[nf * 4 + i] = e5m2f(bptr[i][kb + nf * 16 + c16]);
        // ---- QK^T (setprio: favor MFMA waves vs other blocks' staging) ----
        f32x4 sac[4];
#pragma unroll
        for (int nf = 0; nf < 4; ++nf) sac[nf] = zero;
        __builtin_amdgcn_s_setprio(1);
#pragma unroll
        for (int dk = 0; dk < 2; ++dk) {
#pragma unroll
            for (int nf = 0; nf < 4; ++nf) {
                int r = nf * 16 + c16;
                bf16x8 kf = *(const bf16x8*)&KsC[r * 64 + (((dk * 4 + g) ^ (r & 7)) << 3)];
                sac[nf] = __builtin_amdgcn_mfma_f32_16x16x32_bf16(qf[dk], kf, sac[nf], 0, 0, 0);
            }
        }
        __builtin_amdgcn_s_setprio(0);
        // ---- static-max softmax ----
#pragma unroll
        for (int nf = 0; nf < 4; ++nf)
#pragma unroll
            for (int i = 0; i < 4; ++i) {
                float e = __expf(fmaf(sac[nf][i], 0.125f, bv[nf * 4 + i]));
                sac[nf][i] = e;
                lsum[i] += e;
            }
        // ---- P -> wave-private LDS (chunk-swizzled by g) ----
        short* pbw = &Pb[w][0];
#pragma unroll
        for (int nf = 0; nf < 4; ++nf) {
            int chunkbase = nf * 2 + (c16 >> 3);
            int kpos = c16 & 7;
#pragma unroll
            for (int i = 0; i < 4; ++i)
                pbw[(g * 4 + i) * 72 + (((chunkbase ^ g) & 7) << 3) + kpos] = f2bf(sac[nf][i]);
        }
        // ---- PV (setprio around MFMA cluster) ----
        __builtin_amdgcn_s_setprio(1);
#pragma unroll
        for (int dk = 0; dk < 2; ++dk) {
            bf16x8 pa = *(const bf16x8*)&pbw[c16 * 72 + (((dk * 4 + g) ^ (c16 >> 2)) & 7) * 8];
#pragma unroll
            for (int nf = 0; nf < 4; ++nf) {
                int d = nf * 16 + c16;
                bf16x8 vb = *(const bf16x8*)&VtC[d * 72 + (((dk * 4 + g) ^ (d >> 3)) & 7) * 8];
                oacc[nf] = __builtin_amdgcn_mfma_f32_16x16x32_bf16(pa, vb, oacc[nf], 0, 0, 0);
            }
        }
        __builtin_amdgcn_s_setprio(0);
    }

#pragma unroll
    for (int i = 0; i < 4; ++i) {
#pragma unroll
        for (int off = 1; off < 16; off <<= 1) lsum[i] += __shfl_xor(lsum[i], off, 64);
    }

#pragma unroll
    for (int nf = 0; nf < 4; ++nf)
#pragma unroll
        for (int i = 0; i < 4; ++i) {
            float o = oacc[nf][i] / lsum[i];
            int qq = q0 + w * 16 + g * 4 + i;
            attn_o[(size_t)(b * T_ + qq) * D_ + h * HD_ + nf * 16 + c16] = f2bf(o);
        }
}

// ---------------- launcher ----------------
extern "C" void kernel_launch(void* const* d_in, const int* in_sizes, int n_in,
                              void* d_out, int out_size, void* d_ws, size_t ws_size,
                              hipStream_t stream) {
    const float* x = (const float*)d_in[0];
    const int* rowp = (const int*)d_in[1];
    const int* colp = (const int*)d_in[2];
    const int* drowp = (const int*)d_in[3];
    const int* dcolp = (const int*)d_in[4];
    const int* didp = (const int*)d_in[5];
    // d_in[6] = is_sep (bool) — unused: is_sep <=> demo_id < 0 by construction
    const float* ln1_w = (const float*)d_in[7];
    const float* ln1_b = (const float*)d_in[8];
    const float* ln2_w = (const float*)d_in[9];
    const float* ln2_b = (const float*)d_in[10];
    const float* qkv_w = (const float*)d_in[11];
    const float* qkv_b = (const float*)d_in[12];
    const float* proj_w = (const float*)d_in[13];
    const float* proj_b = (const float*)d_in[14];
    const float* ff1_w = (const float*)d_in[15];
    const float* ff1_b = (const float*)d_in[16];
    const float* ff2_w = (const float*)d_in[17];
    const float* ff2_b = (const float*)d_in[18];
    const float* rel_emb = (const float*)d_in[19];
    const float* demo_emb = (const float*)d_in[20];
    float* out = (float*)d_out;

    const int M = B_ * T_;  // 4096
    char* p = (char*)d_ws;
    short* h1 = (short*)p;     p += (size_t)M * D_ * 2;
    short* qkvb = (short*)p;   p += (size_t)M * 3 * D_ * 2;
    short* attn_o = (short*)p; p += (size_t)M * D_ * 2;
    short* qkvt = (short*)p;   p += (size_t)(3 * D_) * D_ * 2;
    short* projt = (short*)p;  p += (size_t)D_ * D_ * 2;
    short* ff1t = (short*)p;   p += (size_t)FF_ * D_ * 2;
    short* ff2t = (short*)p;   p += (size_t)D_ * FF_ * 2;
    unsigned char* rel8 = (unsigned char*)p;  p += (size_t)SPAN_ * SPAN_ * 16;   // 63.5 KB
    unsigned char* demo8 = (unsigned char*)p; p += (size_t)SPANC_ * SPAN_ * 16;  // 130 KB
    // overlay: biasT (50.3 MB fp8, live until attention) aliases x2+h2+ffact.
    float* x2 = (float*)p;
    short* h2 = (short*)(p + (size_t)M * D_ * 4);
    short* ffact = (short*)(p + (size_t)M * D_ * 4 + (size_t)M * D_ * 2);
    unsigned char* biasT = (unsigned char*)p;

    // ---- precompute ----
    tables8_kernel<<<dim3((SPANC_ * SPAN_ * 12 + 255) / 256), 256, 0, stream>>>(
        rel_emb, demo_emb, rel8, demo8);
    bias_build<<<dim3(T_ / 64, T_ / 16), 256, 0, stream>>>(
        rowp, colp, drowp, dcolp, didp, rel8, demo8, biasT);
    tcast_all<<<dim3(6912), 256, 0, stream>>>(qkv_w, proj_w, ff1_w, ff2_w,
                                              qkvt, projt, ff1t, ff2t);

    // ---- main pipeline ----
    ln_bf16_kernel<<<dim3(M / 4), 256, 0, stream>>>(x, ln1_w, ln1_b, h1);

    gemm_bf16<EPI_NONE, 1, 128><<<dim3(3 * D_ / 128, M / 128), 256, 0, stream>>>(
        h1, qkvt, qkv_b, nullptr, qkvb, M, 3 * D_, D_);

    attn_mfma<<<dim3(B_ * H_ * (T_ / 64)), 256, 0, stream>>>(qkvb, biasT, attn_o);

    gemm_bf16<EPI_RES, 0, 64><<<dim3(D_ / 128, M / 64), 256, 0, stream>>>(
        attn_o, projt, proj_b, x, x2, M, D_, D_);

    ln_bf16_kernel<<<dim3(M / 4), 256, 0, stream>>>(x2, ln2_w, ln2_b, h2);

    gemm_bf16<EPI_GELU, 1, 128><<<dim3(FF_ / 128, M / 128), 256, 0, stream>>>(
        h2, ff1t, ff1_b, nullptr, ffact, M, FF_, D_);

    gemm_bf16<EPI_RES, 0, 64><<<dim3(D_ / 128, M / 64), 256, 0, stream>>>(
        ffact, ff2t, ff2_b, x2, out, M, D_, FF_);
}